// Round 1
// baseline (5164.271 us; speedup 1.0000x reference)
//
#include <hip/hip_runtime.h>
#include <hip/hip_fp16.h>

#define BB 16
#define TT 4096
#define TSZ 64
#define DE 128
#define HH 256
#define LDIM 512
#define ODIM 10
#define NBLKS 6
#define EPSF 1e-5f
#define CL 64
#define NC (TT/CL)        // 64 chunks
#define NROWS (BB*TT)     // 65536

// ---- workspace layout (float offsets) ----
enum : size_t {
  WOFF_Y     = 0,                                   // [B*T*DE] encoder output (residual target)
  WOFF_H     = WOFF_Y + (size_t)NROWS*DE,           // [B*T*DE] running hidden
  WOFF_BGT   = WOFF_H + (size_t)NROWS*DE,           // [NBLK][DE][512] gamma*B^T (re|im)
  WOFF_WC    = WOFF_BGT + (size_t)NBLKS*DE*2*HH,    // [NBLK][512][DE] C-proj weights (re| -im)
  WOFF_LAM   = WOFF_WC + (size_t)NBLKS*2*HH*DE,     // [NBLK][H][2]
  WOFF_LAML  = WOFF_LAM + (size_t)NBLKS*HH*2,       // [NBLK][H][2] lam^CL
  WOFF_ABN   = WOFF_LAML + (size_t)NBLKS*HH*2,      // [NBLK][DE] BN scale*rstd
  WOFF_CBN   = WOFF_ABN + (size_t)NBLKS*DE,         // [NBLK][DE] BN bias-mean*a
  WOFF_SL    = WOFF_CBN + (size_t)NBLKS*DE,         // [B][NC][H][2] chunk-local final states
  WOFF_CARRY = WOFF_SL + (size_t)BB*NC*HH*2,        // [B][NC][H][2] chunk-start carries
  WOFF_STATS = WOFF_CARRY + (size_t)BB*NC*HH*2,     // [NBLK+1][2][DE] sum/sumsq
  WOFF_POOL  = WOFF_STATS + (size_t)(NBLKS+1)*2*DE, // [B][DE]
  WS_FLOATS  = WOFF_POOL + (size_t)BB*DE
};

// ---- dynamic LDS layout (bytes) for k_block ----
#define SOFF_AC  0                          // a[128], c[128]
#define SOFF_DV  1024                       // Dv[128]
#define SOFF_U   1536                       // fp32 [64][128]
#define SOFF_HT  (SOFF_U + CL*DE*4)         // half [64][512]  (Bu -> h_t -> Z1)
#define SOFF_YL  (SOFF_HT + CL*512*2)       // fp32 [64][128]  (ylru; later SRED [32][128][2])
#define SMEM_M0  SOFF_YL                    // 99840 B
#define SMEM_M1  (SOFF_YL + CL*DE*4)        // 132608 B

// ============================ prep: lam/gamma/weight repack ============================
__global__ __launch_bounds__(256) void k_prep(
    const float* __restrict__ nu_log, const float* __restrict__ theta_log,
    const float* __restrict__ B_re, const float* __restrict__ B_im,
    const float* __restrict__ C_re, const float* __restrict__ C_im,
    float* __restrict__ ws)
{
  const int i = blockIdx.x, h = threadIdx.x;
  const float nu  = expf(nu_log[i*HH+h]);
  const float th  = expf(theta_log[i*HH+h]);
  const float mod = expf(-nu);
  const float lr = mod*cosf(th), li = mod*sinf(th);
  const float gamma = sqrtf(fmaxf(1.0f - mod*mod, 1e-8f));
  ws[WOFF_LAM + ((size_t)i*HH+h)*2+0] = lr;
  ws[WOFF_LAM + ((size_t)i*HH+h)*2+1] = li;
  float ar = lr, ai = li;
  #pragma unroll
  for (int q = 0; q < 6; q++) { float nr = ar*ar - ai*ai, ni = 2.0f*ar*ai; ar = nr; ai = ni; }
  ws[WOFF_LAML + ((size_t)i*HH+h)*2+0] = ar;
  ws[WOFF_LAML + ((size_t)i*HH+h)*2+1] = ai;

  float* bgt = ws + WOFF_BGT + (size_t)i*DE*512;
  const float* bre = B_re + ((size_t)i*HH+h)*DE;
  const float* bim = B_im + ((size_t)i*HH+h)*DE;
  for (int d = 0; d < DE; d++) {
    bgt[(size_t)d*512 + h]       = bre[d]*gamma;
    bgt[(size_t)d*512 + 256 + h] = bim[d]*gamma;
  }
  float* wc = ws + WOFF_WC + (size_t)i*512*DE;
  const float* cre = C_re + (size_t)i*DE*HH;
  const float* cim = C_im + (size_t)i*DE*HH;
  for (int d = 0; d < DE; d++) {
    wc[(size_t)h*DE + d]         =  cre[(size_t)d*HH + h];
    wc[(size_t)(256+h)*DE + d]   = -cim[(size_t)d*HH + h];
  }
}

// ============================ encoder: y = x @ W_enc + b_enc (+ stats[0]) ============================
__global__ __launch_bounds__(256) void k_enc(
    const float* __restrict__ x, const float* __restrict__ Wenc,
    const float* __restrict__ benc, float* ws)
{
  __shared__ float XT[CL*TSZ];      // 16 KB
  __shared__ float WE[TSZ*DE];      // 32 KB
  __shared__ float SRED[16*DE*2];   // 16 KB
  const int tid = threadIdx.x;
  const int row0 = blockIdx.x * CL;
  {
    const float4* xg = (const float4*)(x + (size_t)row0*TSZ);
    float4* dst = (float4*)XT;
    for (int idx = tid; idx < CL*TSZ/4; idx += 256) dst[idx] = xg[idx];
    const float4* wg = (const float4*)Wenc;
    float4* dw = (float4*)WE;
    for (int idx = tid; idx < TSZ*DE/4; idx += 256) dw[idx] = wg[idx];
  }
  __syncthreads();
  const int tg = tid >> 4, dg = tid & 15, d0 = dg*8;
  float acc[4][8];
  #pragma unroll
  for (int r = 0; r < 4; r++)
    #pragma unroll
    for (int j = 0; j < 8; j++) acc[r][j] = 0.0f;
  for (int k = 0; k < TSZ; k++) {
    float4 w0 = *(const float4*)&WE[k*DE + d0];
    float4 w1 = *(const float4*)&WE[k*DE + d0 + 4];
    float wv[8] = {w0.x,w0.y,w0.z,w0.w,w1.x,w1.y,w1.z,w1.w};
    #pragma unroll
    for (int r = 0; r < 4; r++) {
      float xv = XT[(tg*4+r)*TSZ + k];
      #pragma unroll
      for (int j = 0; j < 8; j++) acc[r][j] += xv*wv[j];
    }
  }
  float be[8];
  #pragma unroll
  for (int j = 0; j < 8; j++) be[j] = benc[d0+j];
  float* y = ws + WOFF_Y;
  float s[8], ss[8];
  #pragma unroll
  for (int j = 0; j < 8; j++) { s[j] = 0.0f; ss[j] = 0.0f; }
  for (int r = 0; r < 4; r++) {
    const int row = row0 + tg*4 + r;
    float v[8];
    #pragma unroll
    for (int j = 0; j < 8; j++) { v[j] = acc[r][j] + be[j]; s[j] += v[j]; ss[j] += v[j]*v[j]; }
    float4 o0 = {v[0],v[1],v[2],v[3]}, o1 = {v[4],v[5],v[6],v[7]};
    *(float4*)&y[(size_t)row*DE + d0]     = o0;
    *(float4*)&y[(size_t)row*DE + d0 + 4] = o1;
  }
  #pragma unroll
  for (int j = 0; j < 8; j++) {
    SRED[(tg*DE + d0+j)*2+0] = s[j];
    SRED[(tg*DE + d0+j)*2+1] = ss[j];
  }
  __syncthreads();
  {
    const int d = tid >> 1, w = tid & 1;
    float a = 0.0f;
    for (int g = 0; g < 16; g++) a += SRED[(g*DE + d)*2 + w];
    atomicAdd(ws + WOFF_STATS + (size_t)w*DE + d, a);
  }
}

// ============================ BN coef finalize ============================
__global__ void k_coef(const float* __restrict__ scale, const float* __restrict__ bias,
                       float* ws, int i)
{
  const int d = threadIdx.x;  // 128
  const float inv = 1.0f / (float)NROWS;
  const float s  = ws[WOFF_STATS + ((size_t)i*2+0)*DE + d];
  const float sq = ws[WOFF_STATS + ((size_t)i*2+1)*DE + d];
  const float mean = s*inv;
  const float var  = sq*inv - mean*mean;
  const float rstd = rsqrtf(var + EPSF);
  const float a = rstd * scale[i*DE + d];
  ws[WOFF_ABN + (size_t)i*DE + d] = a;
  ws[WOFF_CBN + (size_t)i*DE + d] = bias[i*DE + d] - mean*a;
}

// ============================ carry composition across chunks ============================
__global__ void k_carry(float* ws, int i)
{
  const int h = threadIdx.x;   // 256
  const int b = blockIdx.x;    // 16
  const float Lr = ws[WOFF_LAML + ((size_t)i*HH+h)*2+0];
  const float Li = ws[WOFF_LAML + ((size_t)i*HH+h)*2+1];
  float sr = 0.0f, si = 0.0f;
  ws[WOFF_CARRY + ((size_t)(b*NC+0)*HH + h)*2+0] = 0.0f;
  ws[WOFF_CARRY + ((size_t)(b*NC+0)*HH + h)*2+1] = 0.0f;
  for (int c = 1; c < NC; c++) {
    const float pr = ws[WOFF_SL + ((size_t)(b*NC + c-1)*HH + h)*2+0];
    const float pi = ws[WOFF_SL + ((size_t)(b*NC + c-1)*HH + h)*2+1];
    const float nr = Lr*sr - Li*si + pr;
    const float ni = Lr*si + Li*sr + pi;
    sr = nr; si = ni;
    ws[WOFF_CARRY + ((size_t)(b*NC+c)*HH + h)*2+0] = sr;
    ws[WOFF_CARRY + ((size_t)(b*NC+c)*HH + h)*2+1] = si;
  }
}

// ============================ main fused block kernel ============================
// MODE 0: BN + B-proj + local scan (init 0) -> sL         (LDS: 99840 B)
// MODE 1: BN + B-proj + scan (init carry) + C-proj + MLP + residual + stats (132608 B)
template<int MODE>
__global__ __launch_bounds__(512) void k_block(
    const float* hin, float* ws,
    const float* __restrict__ W1g, const float* __restrict__ b1g,
    const float* __restrict__ W2g, const float* __restrict__ b2g,
    const float* __restrict__ Dvg, int iblk, int islast)
{
  extern __shared__ char smem[];
  float* AC  = (float*)(smem + SOFF_AC);
  float* DVs = (float*)(smem + SOFF_DV);
  float* U   = (float*)(smem + SOFF_U);
  __half* HT = (__half*)(smem + SOFF_HT);
  const int tid = threadIdx.x;
  const int b = blockIdx.y, cb = blockIdx.x;
  const int row0 = b*TT + cb*CL;

  if (tid < DE) {
    AC[tid]      = ws[WOFF_ABN + (size_t)iblk*DE + tid];
    AC[DE + tid] = ws[WOFF_CBN + (size_t)iblk*DE + tid];
    if (MODE == 1) DVs[tid] = Dvg[iblk*DE + tid];
  }
  __syncthreads();
  // P0: load h tile, apply BN -> U
  {
    const float4* hg = (const float4*)(hin + (size_t)row0*DE);
    float4* u4 = (float4*)U;
    for (int idx = tid; idx < CL*DE/4; idx += 512) {
      float4 v = hg[idx];
      const int d0 = (idx*4) & (DE-1);
      v.x = v.x*AC[d0+0] + AC[DE+d0+0];
      v.y = v.y*AC[d0+1] + AC[DE+d0+1];
      v.z = v.z*AC[d0+2] + AC[DE+d0+2];
      v.w = v.w*AC[d0+3] + AC[DE+d0+3];
      u4[idx] = v;
    }
  }
  __syncthreads();
  // P1: Bu = U @ BgT  -> HT (fp16), [64 t][512 hc]
  {
    const float* bgt = ws + WOFF_BGT + (size_t)iblk*DE*512;
    const int tq = tid >> 6, cg = tid & 63, hc0 = cg*8, tb = tq*8;
    float acc[8][8];
    #pragma unroll
    for (int r = 0; r < 8; r++)
      #pragma unroll
      for (int j = 0; j < 8; j++) acc[r][j] = 0.0f;
    for (int k = 0; k < DE; k++) {
      float4 w0 = *(const float4*)&bgt[(size_t)k*512 + hc0];
      float4 w1 = *(const float4*)&bgt[(size_t)k*512 + hc0 + 4];
      float wv[8] = {w0.x,w0.y,w0.z,w0.w,w1.x,w1.y,w1.z,w1.w};
      #pragma unroll
      for (int r = 0; r < 8; r++) {
        float uv = U[(tb+r)*DE + k];
        #pragma unroll
        for (int j = 0; j < 8; j++) acc[r][j] += uv*wv[j];
      }
    }
    #pragma unroll
    for (int r = 0; r < 8; r++)
      #pragma unroll
      for (int j = 0; j < 8; j++)
        HT[(tb+r)*512 + hc0 + j] = __float2half(acc[r][j]);
  }
  __syncthreads();
  // P2: sequential scan over 64 t (threads 0..255 own complex channel h)
  if (tid < HH) {
    const int h = tid;
    const float lr = ws[WOFF_LAM + ((size_t)iblk*HH+h)*2+0];
    const float li = ws[WOFF_LAM + ((size_t)iblk*HH+h)*2+1];
    float sr, si;
    if (MODE == 0) { sr = 0.0f; si = 0.0f; }
    else {
      sr = ws[WOFF_CARRY + ((size_t)(b*NC+cb)*HH + h)*2+0];
      si = ws[WOFF_CARRY + ((size_t)(b*NC+cb)*HH + h)*2+1];
    }
    for (int t = 0; t < CL; t++) {
      const float br = __half2float(HT[t*512 + h]);
      const float bi = __half2float(HT[t*512 + 256 + h]);
      const float nr = lr*sr - li*si + br;
      const float ni = lr*si + li*sr + bi;
      sr = nr; si = ni;
      if (MODE == 1) {
        HT[t*512 + h]       = __float2half(sr);
        HT[t*512 + 256 + h] = __float2half(si);
      }
    }
    if (MODE == 0) {
      ws[WOFF_SL + ((size_t)(b*NC+cb)*HH + h)*2+0] = sr;
      ws[WOFF_SL + ((size_t)(b*NC+cb)*HH + h)*2+1] = si;
    }
  }
  if (MODE == 0) return;
  __syncthreads();
  float* YL = (float*)(smem + SOFF_YL);
  // P3: ylru = Re(C h) + u*D   (K=512)
  {
    const float* wc = ws + WOFF_WC + (size_t)iblk*512*DE;
    const int tg = tid >> 4, dg = tid & 15, d0 = dg*8, t0 = tg*2;
    float a0[8], a1[8];
    #pragma unroll
    for (int j = 0; j < 8; j++) { a0[j] = 0.0f; a1[j] = 0.0f; }
    for (int k = 0; k < 512; k++) {
      float4 w0 = *(const float4*)&wc[(size_t)k*DE + d0];
      float4 w1 = *(const float4*)&wc[(size_t)k*DE + d0 + 4];
      float wv[8] = {w0.x,w0.y,w0.z,w0.w,w1.x,w1.y,w1.z,w1.w};
      const float h0 = __half2float(HT[t0*512 + k]);
      const float h1 = __half2float(HT[(t0+1)*512 + k]);
      #pragma unroll
      for (int j = 0; j < 8; j++) { a0[j] += h0*wv[j]; a1[j] += h1*wv[j]; }
    }
    #pragma unroll
    for (int j = 0; j < 8; j++) {
      const int d = d0 + j;
      YL[t0*DE + d]     = a0[j] + U[t0*DE + d]*DVs[d];
      YL[(t0+1)*DE + d] = a1[j] + U[(t0+1)*DE + d]*DVs[d];
    }
  }
  __syncthreads();
  // P4: z1 = YL @ W1 + b1 -> Z1 (reuses HT region), 4 N-passes of 128
  {
    const float* w1p = W1g + (size_t)iblk*DE*LDIM;
    const float* b1p = b1g + (size_t)iblk*LDIM;
    const int tg = tid >> 4, lg = tid & 15, t0 = tg*2;
    for (int p = 0; p < 4; p++) {
      const int l0 = p*128 + lg*8;
      float a0[8], a1[8];
      #pragma unroll
      for (int j = 0; j < 8; j++) { a0[j] = 0.0f; a1[j] = 0.0f; }
      for (int k = 0; k < DE; k++) {
        float4 w0 = *(const float4*)&w1p[(size_t)k*LDIM + l0];
        float4 w1v = *(const float4*)&w1p[(size_t)k*LDIM + l0 + 4];
        float wv[8] = {w0.x,w0.y,w0.z,w0.w,w1v.x,w1v.y,w1v.z,w1v.w};
        const float y0 = YL[t0*DE + k];
        const float y1 = YL[(t0+1)*DE + k];
        #pragma unroll
        for (int j = 0; j < 8; j++) { a0[j] += y0*wv[j]; a1[j] += y1*wv[j]; }
      }
      #pragma unroll
      for (int j = 0; j < 8; j++) {
        HT[t0*512 + l0 + j]     = __float2half(a0[j] + b1p[l0+j]);
        HT[(t0+1)*512 + l0 + j] = __float2half(a1[j] + b1p[l0+j]);
      }
    }
  }
  __syncthreads();
  // P5: GLU -> G (reuses U region as half [64][256])
  {
    __half* G = (__half*)(smem + SOFF_U);
    for (int idx = tid; idx < CL*256; idx += 512) {
      const int t = idx >> 8, j = idx & 255;
      const float av = __half2float(HT[t*512 + j]);
      const float bv = __half2float(HT[t*512 + 256 + j]);
      G[t*256 + j] = __float2half(av / (1.0f + expf(-bv)));
    }
  }
  __syncthreads();
  // P6: h_new = G @ W2 + b2 + y   (K=256), write global + stats partials
  {
    const __half* G = (const __half*)(smem + SOFF_U);
    float* SRED = YL;  // [32][128][2]
    const float* w2p = W2g + (size_t)iblk*256*DE;
    const float* b2p = b2g + (size_t)iblk*DE;
    const int tg = tid >> 4, dg = tid & 15, d0 = dg*8, t0 = tg*2;
    float a0[8], a1[8];
    #pragma unroll
    for (int j = 0; j < 8; j++) { a0[j] = 0.0f; a1[j] = 0.0f; }
    for (int k = 0; k < 256; k++) {
      float4 w0 = *(const float4*)&w2p[(size_t)k*DE + d0];
      float4 w1v = *(const float4*)&w2p[(size_t)k*DE + d0 + 4];
      float wv[8] = {w0.x,w0.y,w0.z,w0.w,w1v.x,w1v.y,w1v.z,w1v.w};
      const float g0 = __half2float(G[t0*256 + k]);
      const float g1 = __half2float(G[(t0+1)*256 + k]);
      #pragma unroll
      for (int j = 0; j < 8; j++) { a0[j] += g0*wv[j]; a1[j] += g1*wv[j]; }
    }
    const float* yg = ws + WOFF_Y + (size_t)(row0 + t0)*DE;
    float* hg = ws + WOFF_H + (size_t)(row0 + t0)*DE;
    float4 ya0 = *(const float4*)&yg[d0], ya1 = *(const float4*)&yg[d0+4];
    float4 yb0 = *(const float4*)&yg[DE + d0], yb1 = *(const float4*)&yg[DE + d0+4];
    float yv0[8] = {ya0.x,ya0.y,ya0.z,ya0.w,ya1.x,ya1.y,ya1.z,ya1.w};
    float yv1[8] = {yb0.x,yb0.y,yb0.z,yb0.w,yb1.x,yb1.y,yb1.z,yb1.w};
    float v0[8], v1[8];
    #pragma unroll
    for (int j = 0; j < 8; j++) {
      const float bb = b2p[d0+j];
      v0[j] = a0[j] + bb + yv0[j];
      v1[j] = a1[j] + bb + yv1[j];
    }
    float4 o;
    o = {v0[0],v0[1],v0[2],v0[3]}; *(float4*)&hg[d0]      = o;
    o = {v0[4],v0[5],v0[6],v0[7]}; *(float4*)&hg[d0+4]    = o;
    o = {v1[0],v1[1],v1[2],v1[3]}; *(float4*)&hg[DE+d0]   = o;
    o = {v1[4],v1[5],v1[6],v1[7]}; *(float4*)&hg[DE+d0+4] = o;
    #pragma unroll
    for (int j = 0; j < 8; j++) {
      SRED[(tg*DE + d0+j)*2+0] = v0[j] + v1[j];
      SRED[(tg*DE + d0+j)*2+1] = v0[j]*v0[j] + v1[j]*v1[j];
    }
  }
  __syncthreads();
  // P7: reduce stats + pooled
  if (tid < 256) {
    float* SRED = (float*)(smem + SOFF_YL);
    const int d = tid >> 1, w = tid & 1;
    float a = 0.0f;
    for (int g = 0; g < 32; g++) a += SRED[(g*DE + d)*2 + w];
    atomicAdd(ws + WOFF_STATS + (size_t)((iblk+1)*2 + w)*DE + d, a);
    if (islast && w == 0) atomicAdd(ws + WOFF_POOL + (size_t)b*DE + d, a);
  }
}

// ============================ final projection ============================
__global__ void k_out(const float* __restrict__ Wout, const float* __restrict__ bout,
                      const float* __restrict__ ws, float* __restrict__ out)
{
  const int tid = threadIdx.x;
  if (tid < BB*ODIM) {
    const int b = tid / ODIM, o = tid % ODIM;
    float acc = bout[o];
    const float* p = ws + WOFF_POOL + (size_t)b*DE;
    const float invT = 1.0f / (float)TT;
    for (int d = 0; d < DE; d++) acc += p[d]*invT*Wout[d*ODIM + o];
    out[tid] = acc;
  }
}

extern "C" void kernel_launch(void* const* d_in, const int* in_sizes, int n_in,
                              void* d_out, int out_size, void* d_ws, size_t ws_size,
                              hipStream_t stream)
{
  const float* x   = (const float*)d_in[0];
  const float* nu  = (const float*)d_in[1];
  const float* th  = (const float*)d_in[2];
  const float* Bre = (const float*)d_in[3];
  const float* Bim = (const float*)d_in[4];
  const float* Cre = (const float*)d_in[5];
  const float* Cim = (const float*)d_in[6];
  const float* Dv  = (const float*)d_in[7];
  const float* W1  = (const float*)d_in[8];
  const float* b1  = (const float*)d_in[9];
  const float* W2  = (const float*)d_in[10];
  const float* b2  = (const float*)d_in[11];
  const float* bns = (const float*)d_in[12];
  const float* bnb = (const float*)d_in[13];
  const float* We  = (const float*)d_in[14];
  const float* be  = (const float*)d_in[15];
  const float* Wo  = (const float*)d_in[16];
  const float* bo  = (const float*)d_in[17];
  float* ws = (float*)d_ws;
  float* out = (float*)d_out;

  // allow >64KB dynamic LDS (gfx950 has 160 KiB/CU); harmless if already set
  (void)hipFuncSetAttribute((const void*)k_block<0>,
        hipFuncAttributeMaxDynamicSharedMemorySize, SMEM_M0);
  (void)hipFuncSetAttribute((const void*)k_block<1>,
        hipFuncAttributeMaxDynamicSharedMemorySize, SMEM_M1);

  // zero stats + pooled accumulators
  hipMemsetAsync(ws + WOFF_STATS, 0,
                 (size_t)(((NBLKS+1)*2*DE) + BB*DE)*sizeof(float), stream);

  k_prep<<<NBLKS, 256, 0, stream>>>(nu, th, Bre, Bim, Cre, Cim, ws);
  k_enc<<<NROWS/CL, 256, 0, stream>>>(x, We, be, ws);

  for (int i = 0; i < NBLKS; i++) {
    const float* hin = (i == 0) ? (ws + WOFF_Y) : (ws + WOFF_H);
    k_coef<<<1, 128, 0, stream>>>(bns, bnb, ws, i);
    k_block<0><<<dim3(NC, BB), 512, SMEM_M0, stream>>>(hin, ws, W1, b1, W2, b2, Dv, i, 0);
    k_carry<<<BB, 256, 0, stream>>>(ws, i);
    k_block<1><<<dim3(NC, BB), 512, SMEM_M1, stream>>>(hin, ws, W1, b1, W2, b2, Dv, i,
                                                       (i == NBLKS-1) ? 1 : 0);
  }
  k_out<<<1, 256, 0, stream>>>(Wo, bo, ws, out);
}

// Round 2
// 1043.005 us; speedup vs baseline: 4.9513x; 4.9513x over previous
//
#include <hip/hip_runtime.h>
#include <hip/hip_fp16.h>

#define BB 16
#define TT 4096
#define TSZ 64
#define DE 128
#define HH 256
#define LDIM 512
#define ODIM 10
#define NBLKS 6
#define EPSF 1e-5f
#define CL 64
#define NC (TT/CL)        // 64 chunks
#define NROWS (BB*TT)     // 65536

typedef _Float16 f16x8 __attribute__((ext_vector_type(8)));
typedef float f32x4 __attribute__((ext_vector_type(4)));
#define MFMA16(a,b,c) __builtin_amdgcn_mfma_f32_16x16x32_f16((a),(b),(c),0,0,0)

// ---- f16 weight region layout (offsets in halfs, base = ws + WOFF_W16) ----
enum : size_t {
  HOFF_BG = 0,                                  // [NBLK][512][128]  (gamma*B, re|im rows)
  HOFF_WC = HOFF_BG + (size_t)NBLKS*512*128,    // [NBLK][128][512]  (C-proj, [d][hc])
  HOFF_W1 = HOFF_WC + (size_t)NBLKS*128*512,    // [NBLK][512][128]  (W1^T [l][d])
  HOFF_W2 = HOFF_W1 + (size_t)NBLKS*512*128,    // [NBLK][128][256]  (W2^T [d][g])
  HOFF_WE = HOFF_W2 + (size_t)NBLKS*128*256,    // [128][64]         (Wenc^T [d][k])
  HTOT_HALFS = HOFF_WE + 128*64
};

// ---- workspace layout (float offsets) ----
enum : size_t {
  WOFF_Y     = 0,                                   // [B*T*DE] encoder output
  WOFF_H     = WOFF_Y + (size_t)NROWS*DE,           // [B*T*DE] running hidden
  WOFF_W16   = WOFF_H + (size_t)NROWS*DE,           // f16 weights region
  WOFF_LAM   = WOFF_W16 + (HTOT_HALFS+1)/2,         // [NBLK][H][2]
  WOFF_LAML  = WOFF_LAM + (size_t)NBLKS*HH*2,       // [NBLK][H][2] lam^CL
  WOFF_ABN   = WOFF_LAML + (size_t)NBLKS*HH*2,      // [NBLK][DE]
  WOFF_CBN   = WOFF_ABN + (size_t)NBLKS*DE,         // [NBLK][DE]
  WOFF_SL    = WOFF_CBN + (size_t)NBLKS*DE,         // [B][NC][H][2]
  WOFF_CARRY = WOFF_SL + (size_t)BB*NC*HH*2,        // [B][NC][H][2]
  WOFF_STATS = WOFF_CARRY + (size_t)BB*NC*HH*2,     // [NBLK+1][2][DE]
  WOFF_POOL  = WOFF_STATS + (size_t)(NBLKS+1)*2*DE, // [B][DE]
  WS_FLOATS  = WOFF_POOL + (size_t)BB*DE
};

// ---- dynamic LDS layout (bytes) for k_block ----
#define SOFF_AC  0                          // f32 a[128], c[128]
#define SOFF_DV  1024                       // f32 [128]
#define SOFF_U   1536                       // half [64][136]
#define SOFF_YL  (SOFF_U + 64*136*2)        // half [64][136]   (18944)
#define SOFF_HT  (SOFF_YL + 64*136*2)       // half [64][520]   (36352)
#define SOFF_G   SOFF_U                     // half [64][264] overlays U+YL
#define SMEM_SZ  (SOFF_HT + 64*520*2)       // 102912 B

// ============================ prep: lam + f16 weight repack ============================
__global__ __launch_bounds__(256) void k_prep(
    const float* __restrict__ nu_log, const float* __restrict__ theta_log,
    const float* __restrict__ B_re, const float* __restrict__ B_im,
    const float* __restrict__ C_re, const float* __restrict__ C_im,
    const float* __restrict__ W1g, const float* __restrict__ W2g,
    const float* __restrict__ Wenc, float* ws)
{
  const int i = blockIdx.x, h = threadIdx.x;
  __half* w16 = (__half*)(ws + WOFF_W16);
  const float nu  = expf(nu_log[i*HH+h]);
  const float th  = expf(theta_log[i*HH+h]);
  const float mod = expf(-nu);
  const float lr = mod*cosf(th), li = mod*sinf(th);
  const float gamma = sqrtf(fmaxf(1.0f - mod*mod, 1e-8f));
  ws[WOFF_LAM + ((size_t)i*HH+h)*2+0] = lr;
  ws[WOFF_LAM + ((size_t)i*HH+h)*2+1] = li;
  float ar = lr, ai = li;
  #pragma unroll
  for (int q = 0; q < 6; q++) { float nr = ar*ar - ai*ai, ni = 2.0f*ar*ai; ar = nr; ai = ni; }
  ws[WOFF_LAML + ((size_t)i*HH+h)*2+0] = ar;
  ws[WOFF_LAML + ((size_t)i*HH+h)*2+1] = ai;

  // BG [512][128]: rows 0..255 = gamma*B_re[h][:], 256..511 = gamma*B_im[h][:]
  {
    __half* bg = w16 + HOFF_BG + (size_t)i*512*128;
    const float* bre = B_re + ((size_t)i*HH+h)*DE;
    const float* bim = B_im + ((size_t)i*HH+h)*DE;
    for (int d = 0; d < DE; d++) {
      bg[(size_t)h*128 + d]       = __float2half(bre[d]*gamma);
      bg[(size_t)(256+h)*128 + d] = __float2half(bim[d]*gamma);
    }
  }
  // WC [128][512]: [d][hc], hc<256 = C_re[d][hc], hc>=256 = -C_im[d][hc-256]
  {
    __half* wc = w16 + HOFF_WC + (size_t)i*128*512;
    const float* cre = C_re + (size_t)i*DE*HH;
    const float* cim = C_im + (size_t)i*DE*HH;
    for (int d = 0; d < DE; d++) {
      wc[(size_t)d*512 + h]       = __float2half( cre[(size_t)d*HH + h]);
      wc[(size_t)d*512 + 256 + h] = __float2half(-cim[(size_t)d*HH + h]);
    }
  }
  // W1T [512][128]: [l][d]
  {
    __half* w1t = w16 + HOFF_W1 + (size_t)i*512*128;
    for (int d = 0; d < DE; d++) {
      w1t[(size_t)h*128 + d]       = __float2half(W1g[((size_t)i*DE + d)*LDIM + h]);
      w1t[(size_t)(256+h)*128 + d] = __float2half(W1g[((size_t)i*DE + d)*LDIM + 256 + h]);
    }
  }
  // W2T [128][256]: [d][g]
  if (h < 128) {
    __half* w2t = w16 + HOFF_W2 + (size_t)i*128*256;
    for (int g = 0; g < 256; g++)
      w2t[(size_t)h*256 + g] = __float2half(W2g[((size_t)i*256 + g)*DE + h]);
  }
  // WencT [128][64] (block 0 only)
  if (i == 0 && h < 128) {
    __half* wet = w16 + HOFF_WE;
    for (int k = 0; k < TSZ; k++)
      wet[(size_t)h*TSZ + k] = __float2half(Wenc[(size_t)k*DE + h]);
  }
}

// ============================ encoder (MFMA) ============================
__global__ __launch_bounds__(512) void k_enc(
    const float* __restrict__ x, const float* __restrict__ benc, float* ws)
{
  __shared__ __half XT[64*72];
  const int tid = threadIdx.x, w = tid >> 6, l = tid & 63;
  const size_t row0 = (size_t)blockIdx.x * CL;
  {
    const float4* xg = (const float4*)(x + row0*TSZ);
    for (int idx = tid; idx < 1024; idx += 512) {
      float4 v = xg[idx];
      const int r = idx >> 4, c4 = (idx & 15)*4;
      *(__half2*)&XT[r*72 + c4]     = __half2{__float2half(v.x), __float2half(v.y)};
      *(__half2*)&XT[r*72 + c4 + 2] = __half2{__float2half(v.z), __float2half(v.w)};
    }
  }
  __syncthreads();
  const __half* wet = (const __half*)(ws + WOFF_W16) + HOFF_WE;
  const int n0 = w*16;
  f32x4 acc[4];
  #pragma unroll
  for (int mt = 0; mt < 4; mt++) acc[mt] = (f32x4)(0.0f);
  #pragma unroll
  for (int k0 = 0; k0 < 64; k0 += 32) {
    f16x8 bf = *(const f16x8*)&wet[(size_t)(n0 + (l&15))*64 + k0 + (l>>4)*8];
    #pragma unroll
    for (int mt = 0; mt < 4; mt++) {
      f16x8 af = *(const f16x8*)&XT[(mt*16 + (l&15))*72 + k0 + (l>>4)*8];
      acc[mt] = MFMA16(af, bf, acc[mt]);
    }
  }
  const int d = n0 + (l&15);
  const float be = benc[d];
  float s = 0.0f, ss = 0.0f;
  float* y = ws + WOFF_Y;
  #pragma unroll
  for (int mt = 0; mt < 4; mt++)
    #pragma unroll
    for (int j = 0; j < 4; j++) {
      const int t = mt*16 + (l>>4)*4 + j;
      const float v = acc[mt][j] + be;
      y[(row0 + t)*DE + d] = v;
      s += v; ss += v*v;
    }
  s  += __shfl_xor(s, 16);  s  += __shfl_xor(s, 32);
  ss += __shfl_xor(ss, 16); ss += __shfl_xor(ss, 32);
  if (l < 16) {
    atomicAdd(ws + WOFF_STATS + d, s);
    atomicAdd(ws + WOFF_STATS + DE + d, ss);
  }
}

// ============================ BN coef finalize ============================
__global__ void k_coef(const float* __restrict__ scale, const float* __restrict__ bias,
                       float* ws, int i)
{
  const int d = threadIdx.x;  // 128
  const float inv = 1.0f / (float)NROWS;
  const float s  = ws[WOFF_STATS + ((size_t)i*2+0)*DE + d];
  const float sq = ws[WOFF_STATS + ((size_t)i*2+1)*DE + d];
  const float mean = s*inv;
  const float var  = sq*inv - mean*mean;
  const float rstd = rsqrtf(var + EPSF);
  const float a = rstd * scale[i*DE + d];
  ws[WOFF_ABN + (size_t)i*DE + d] = a;
  ws[WOFF_CBN + (size_t)i*DE + d] = bias[i*DE + d] - mean*a;
}

// ============================ carry composition across chunks ============================
__global__ void k_carry(float* ws, int i)
{
  const int h = threadIdx.x;   // 256
  const int b = blockIdx.x;    // 16
  const float Lr = ws[WOFF_LAML + ((size_t)i*HH+h)*2+0];
  const float Li = ws[WOFF_LAML + ((size_t)i*HH+h)*2+1];
  float sr = 0.0f, si = 0.0f;
  ws[WOFF_CARRY + ((size_t)(b*NC+0)*HH + h)*2+0] = 0.0f;
  ws[WOFF_CARRY + ((size_t)(b*NC+0)*HH + h)*2+1] = 0.0f;
  for (int c = 1; c < NC; c++) {
    const float pr = ws[WOFF_SL + ((size_t)(b*NC + c-1)*HH + h)*2+0];
    const float pi = ws[WOFF_SL + ((size_t)(b*NC + c-1)*HH + h)*2+1];
    const float nr = Lr*sr - Li*si + pr;
    const float ni = Lr*si + Li*sr + pi;
    sr = nr; si = ni;
    ws[WOFF_CARRY + ((size_t)(b*NC+c)*HH + h)*2+0] = sr;
    ws[WOFF_CARRY + ((size_t)(b*NC+c)*HH + h)*2+1] = si;
  }
}

// ============================ main fused block kernel (MFMA) ============================
// MODE 0: BN + B-proj + local scan -> SL
// MODE 1: BN + B-proj + scan(carry) + C-proj + MLP + residual + stats
template<int MODE>
__global__ __launch_bounds__(512) void k_block(
    const float* hin, float* ws,
    const float* __restrict__ b1g, const float* __restrict__ b2g,
    const float* __restrict__ Dvg, int iblk, int islast)
{
  extern __shared__ char smem[];
  float* AC  = (float*)(smem + SOFF_AC);
  float* DVs = (float*)(smem + SOFF_DV);
  __half* U  = (__half*)(smem + SOFF_U);
  __half* YL = (__half*)(smem + SOFF_YL);
  __half* G  = (__half*)(smem + SOFF_G);
  __half* HT = (__half*)(smem + SOFF_HT);
  const __half* w16 = (const __half*)(ws + WOFF_W16);
  const int tid = threadIdx.x, w = tid >> 6, l = tid & 63;
  const int b = blockIdx.y, cb = blockIdx.x;
  const int row0 = b*TT + cb*CL;

  if (tid < DE) {
    AC[tid]      = ws[WOFF_ABN + (size_t)iblk*DE + tid];
    AC[DE + tid] = ws[WOFF_CBN + (size_t)iblk*DE + tid];
    if (MODE == 1) DVs[tid] = Dvg[iblk*DE + tid];
  }
  __syncthreads();
  // P0: load h tile, BN -> U (f16, stride 136)
  {
    const float4* hg = (const float4*)(hin + (size_t)row0*DE);
    for (int idx = tid; idx < CL*DE/4; idx += 512) {
      float4 v = hg[idx];
      const int row = idx >> 5, d0 = (idx & 31)*4;
      const float v0 = v.x*AC[d0+0] + AC[DE+d0+0];
      const float v1 = v.y*AC[d0+1] + AC[DE+d0+1];
      const float v2 = v.z*AC[d0+2] + AC[DE+d0+2];
      const float v3 = v.w*AC[d0+3] + AC[DE+d0+3];
      *(__half2*)&U[row*136 + d0]     = __half2{__float2half(v0), __float2half(v1)};
      *(__half2*)&U[row*136 + d0 + 2] = __half2{__float2half(v2), __float2half(v3)};
    }
  }
  __syncthreads();
  // P1: Bu = U @ BG^T -> HT [64][520]  (M=64,N=512,K=128); wave: all M, N=64
  {
    const __half* BG = w16 + HOFF_BG + (size_t)iblk*512*128;
    const int n0 = w*64;
    f32x4 acc[4][4];
    #pragma unroll
    for (int mt = 0; mt < 4; mt++)
      #pragma unroll
      for (int nt = 0; nt < 4; nt++) acc[mt][nt] = (f32x4)(0.0f);
    #pragma unroll
    for (int k0 = 0; k0 < 128; k0 += 32) {
      f16x8 af[4], bf[4];
      #pragma unroll
      for (int mt = 0; mt < 4; mt++)
        af[mt] = *(const f16x8*)&U[(mt*16 + (l&15))*136 + k0 + (l>>4)*8];
      #pragma unroll
      for (int nt = 0; nt < 4; nt++)
        bf[nt] = *(const f16x8*)&BG[(size_t)(n0 + nt*16 + (l&15))*128 + k0 + (l>>4)*8];
      #pragma unroll
      for (int mt = 0; mt < 4; mt++)
        #pragma unroll
        for (int nt = 0; nt < 4; nt++)
          acc[mt][nt] = MFMA16(af[mt], bf[nt], acc[mt][nt]);
    }
    #pragma unroll
    for (int mt = 0; mt < 4; mt++)
      #pragma unroll
      for (int nt = 0; nt < 4; nt++)
        #pragma unroll
        for (int j = 0; j < 4; j++)
          HT[(mt*16 + (l>>4)*4 + j)*520 + n0 + nt*16 + (l&15)] = __float2half(acc[mt][nt][j]);
  }
  __syncthreads();
  // P2: sequential scan over 64 t (threads 0..255 own channel h)
  if (tid < HH) {
    const int h = tid;
    const float lr = ws[WOFF_LAM + ((size_t)iblk*HH+h)*2+0];
    const float li = ws[WOFF_LAM + ((size_t)iblk*HH+h)*2+1];
    float sr, si;
    if (MODE == 0) { sr = 0.0f; si = 0.0f; }
    else {
      sr = ws[WOFF_CARRY + ((size_t)(b*NC+cb)*HH + h)*2+0];
      si = ws[WOFF_CARRY + ((size_t)(b*NC+cb)*HH + h)*2+1];
    }
    for (int t = 0; t < CL; t++) {
      const float br = __half2float(HT[t*520 + h]);
      const float bi = __half2float(HT[t*520 + 256 + h]);
      const float nr = lr*sr - li*si + br;
      const float ni = lr*si + li*sr + bi;
      sr = nr; si = ni;
      if (MODE == 1) {
        HT[t*520 + h]       = __float2half(sr);
        HT[t*520 + 256 + h] = __float2half(si);
      }
    }
    if (MODE == 0) {
      ws[WOFF_SL + ((size_t)(b*NC+cb)*HH + h)*2+0] = sr;
      ws[WOFF_SL + ((size_t)(b*NC+cb)*HH + h)*2+1] = si;
    }
  }
  if (MODE == 0) return;
  __syncthreads();
  // P3: ylru = Re(C h) + u*D  (M=64,N=128,K=512); wave: all M, N=16
  {
    const __half* WC = w16 + HOFF_WC + (size_t)iblk*128*512;
    const int n0 = w*16;
    f32x4 acc[4];
    #pragma unroll
    for (int mt = 0; mt < 4; mt++) acc[mt] = (f32x4)(0.0f);
    for (int k0 = 0; k0 < 512; k0 += 32) {
      f16x8 bf = *(const f16x8*)&WC[(size_t)(n0 + (l&15))*512 + k0 + (l>>4)*8];
      #pragma unroll
      for (int mt = 0; mt < 4; mt++) {
        f16x8 af = *(const f16x8*)&HT[(mt*16 + (l&15))*520 + k0 + (l>>4)*8];
        acc[mt] = MFMA16(af, bf, acc[mt]);
      }
    }
    const int d = n0 + (l&15);
    const float dv = DVs[d];
    #pragma unroll
    for (int mt = 0; mt < 4; mt++)
      #pragma unroll
      for (int j = 0; j < 4; j++) {
        const int t = mt*16 + (l>>4)*4 + j;
        const float v = acc[mt][j] + __half2float(U[t*136 + d])*dv;
        YL[t*136 + d] = __float2half(v);
      }
  }
  __syncthreads();
  // P4: Z1 = YL @ W1 + b1 -> HT  (M=64,N=512,K=128); wave: all M, N=64
  {
    const __half* W1T = w16 + HOFF_W1 + (size_t)iblk*512*128;
    const int n0 = w*64;
    f32x4 acc[4][4];
    #pragma unroll
    for (int mt = 0; mt < 4; mt++)
      #pragma unroll
      for (int nt = 0; nt < 4; nt++) acc[mt][nt] = (f32x4)(0.0f);
    #pragma unroll
    for (int k0 = 0; k0 < 128; k0 += 32) {
      f16x8 af[4], bf[4];
      #pragma unroll
      for (int mt = 0; mt < 4; mt++)
        af[mt] = *(const f16x8*)&YL[(mt*16 + (l&15))*136 + k0 + (l>>4)*8];
      #pragma unroll
      for (int nt = 0; nt < 4; nt++)
        bf[nt] = *(const f16x8*)&W1T[(size_t)(n0 + nt*16 + (l&15))*128 + k0 + (l>>4)*8];
      #pragma unroll
      for (int mt = 0; mt < 4; mt++)
        #pragma unroll
        for (int nt = 0; nt < 4; nt++)
          acc[mt][nt] = MFMA16(af[mt], bf[nt], acc[mt][nt]);
    }
    #pragma unroll
    for (int nt = 0; nt < 4; nt++) {
      const int col = n0 + nt*16 + (l&15);
      const float bb = b1g[(size_t)iblk*LDIM + col];
      #pragma unroll
      for (int mt = 0; mt < 4; mt++)
        #pragma unroll
        for (int j = 0; j < 4; j++)
          HT[(mt*16 + (l>>4)*4 + j)*520 + col] = __float2half(acc[mt][nt][j] + bb);
    }
  }
  __syncthreads();
  // P5: GLU -> G [64][264]
  for (int idx = tid; idx < CL*256; idx += 512) {
    const int t = idx >> 8, j = idx & 255;
    const float av = __half2float(HT[t*520 + j]);
    const float bv = __half2float(HT[t*520 + 256 + j]);
    G[t*264 + j] = __float2half(av / (1.0f + __expf(-bv)));
  }
  __syncthreads();
  // P6: h_new = G @ W2 + b2 + y  (M=64,N=128,K=256); wave: all M, N=16
  {
    const __half* W2T = w16 + HOFF_W2 + (size_t)iblk*128*256;
    const int n0 = w*16;
    const int d = n0 + (l&15);
    f32x4 acc[4];
    #pragma unroll
    for (int mt = 0; mt < 4; mt++) acc[mt] = (f32x4)(0.0f);
    #pragma unroll
    for (int k0 = 0; k0 < 256; k0 += 32) {
      f16x8 bf = *(const f16x8*)&W2T[(size_t)d*256 + k0 + (l>>4)*8];
      #pragma unroll
      for (int mt = 0; mt < 4; mt++) {
        f16x8 af = *(const f16x8*)&G[(mt*16 + (l&15))*264 + k0 + (l>>4)*8];
        acc[mt] = MFMA16(af, bf, acc[mt]);
      }
    }
    const float bb = b2g[(size_t)iblk*DE + d];
    float s = 0.0f, ss = 0.0f;
    #pragma unroll
    for (int mt = 0; mt < 4; mt++)
      #pragma unroll
      for (int j = 0; j < 4; j++) {
        const int t = mt*16 + (l>>4)*4 + j;
        const size_t row = (size_t)(row0 + t);
        const float v = acc[mt][j] + bb + ws[WOFF_Y + row*DE + d];
        ws[WOFF_H + row*DE + d] = v;
        s += v; ss += v*v;
      }
    s  += __shfl_xor(s, 16);  s  += __shfl_xor(s, 32);
    ss += __shfl_xor(ss, 16); ss += __shfl_xor(ss, 32);
    if (l < 16) {
      atomicAdd(ws + WOFF_STATS + (size_t)((iblk+1)*2 + 0)*DE + d, s);
      atomicAdd(ws + WOFF_STATS + (size_t)((iblk+1)*2 + 1)*DE + d, ss);
      if (islast) atomicAdd(ws + WOFF_POOL + (size_t)b*DE + d, s);
    }
  }
}

// ============================ final projection ============================
__global__ void k_out(const float* __restrict__ Wout, const float* __restrict__ bout,
                      const float* __restrict__ ws, float* __restrict__ out)
{
  const int tid = threadIdx.x;
  if (tid < BB*ODIM) {
    const int b = tid / ODIM, o = tid % ODIM;
    float acc = bout[o];
    const float* p = ws + WOFF_POOL + (size_t)b*DE;
    const float invT = 1.0f / (float)TT;
    for (int d = 0; d < DE; d++) acc += p[d]*invT*Wout[d*ODIM + o];
    out[tid] = acc;
  }
}

extern "C" void kernel_launch(void* const* d_in, const int* in_sizes, int n_in,
                              void* d_out, int out_size, void* d_ws, size_t ws_size,
                              hipStream_t stream)
{
  const float* x   = (const float*)d_in[0];
  const float* nu  = (const float*)d_in[1];
  const float* th  = (const float*)d_in[2];
  const float* Bre = (const float*)d_in[3];
  const float* Bim = (const float*)d_in[4];
  const float* Cre = (const float*)d_in[5];
  const float* Cim = (const float*)d_in[6];
  const float* Dv  = (const float*)d_in[7];
  const float* W1  = (const float*)d_in[8];
  const float* b1  = (const float*)d_in[9];
  const float* W2  = (const float*)d_in[10];
  const float* b2  = (const float*)d_in[11];
  const float* bns = (const float*)d_in[12];
  const float* bnb = (const float*)d_in[13];
  const float* We  = (const float*)d_in[14];
  const float* be  = (const float*)d_in[15];
  const float* Wo  = (const float*)d_in[16];
  const float* bo  = (const float*)d_in[17];
  float* ws = (float*)d_ws;
  float* out = (float*)d_out;

  (void)hipFuncSetAttribute((const void*)k_block<0>,
        hipFuncAttributeMaxDynamicSharedMemorySize, SMEM_SZ);
  (void)hipFuncSetAttribute((const void*)k_block<1>,
        hipFuncAttributeMaxDynamicSharedMemorySize, SMEM_SZ);

  // zero stats + pooled accumulators
  hipMemsetAsync(ws + WOFF_STATS, 0,
                 (size_t)(((NBLKS+1)*2*DE) + BB*DE)*sizeof(float), stream);

  k_prep<<<NBLKS, 256, 0, stream>>>(nu, th, Bre, Bim, Cre, Cim, W1, W2, We, ws);
  k_enc<<<NROWS/CL, 512, 0, stream>>>(x, be, ws);

  for (int i = 0; i < NBLKS; i++) {
    const float* hin = (i == 0) ? (ws + WOFF_Y) : (ws + WOFF_H);
    k_coef<<<1, 128, 0, stream>>>(bns, bnb, ws, i);
    k_block<0><<<dim3(NC, BB), 512, SMEM_SZ, stream>>>(hin, ws, b1, b2, Dv, i, 0);
    k_carry<<<BB, 256, 0, stream>>>(ws, i);
    k_block<1><<<dim3(NC, BB), 512, SMEM_SZ, stream>>>(hin, ws, b1, b2, Dv, i,
                                                       (i == NBLKS-1) ? 1 : 0);
  }
  k_out<<<1, 256, 0, stream>>>(Wo, bo, ws, out);
}